// Round 3
// baseline (74.169 us; speedup 1.0000x reference)
//
#include <hip/hip_runtime.h>
#include <hip/hip_cooperative_groups.h>
#include <hip/hip_bf16.h>
#include <math.h>

#define NN 384   // 2*B
#define BB 192   // B
#define DD 128   // feature dim

namespace cg = cooperative_groups;

// TEMP=2.0 -> s = -dist*0.5 ; TAU=1.0 ; POS_W=0.1 ; NEG_W=1.0 ; SOFT=true
//
// denom[i,p] = Wtot_i + sum_{j: |yi-yj| < |yi-yp|} (c1_j - w_j)
// The j-set is a contiguous interval in y-sorted order; ranks are
// row-independent and computed per block from the 192 distinct targets.

__global__ __launch_bounds__(NN) void fused_kernel(
    const float* __restrict__ emb,     // [192,2,128]
    const float* __restrict__ tgt,     // [192,1]
    float* __restrict__ partial,       // d_ws: NN floats, fully rewritten
    float* __restrict__ out)           // [1]
{
    const int i = blockIdx.x;
    const int t = threadIdx.x;

    __shared__ float yb[BB];           // distinct targets
    __shared__ float zi[DD];
    __shared__ float ys[NN];           // y sorted
    __shared__ float dsort[NN];        // (c1-w) scattered to sorted order
    __shared__ float P[NN + 1];        // exclusive prefix sums
    __shared__ float wavesum[NN / 64];
    __shared__ float part[NN / 64];
    __shared__ float wtot_sh;

    if (t < BB) yb[t] = tgt[t];
    const int ioff = (i < BB) ? i * 2 * DD : ((i - BB) * 2 + 1) * DD;
    if (t < DD) zi[t] = emb[ioff + t];
    __syncthreads();

    // ---- rank of element t in stable y-sort (row-independent) ----
    const int b = (t < BB) ? t : t - BB;
    const float yj = yb[b];
    int cnt = 0;
#pragma unroll 4
    for (int q = 0; q < BB; ++q) {
        const float yq = yb[q];
        cnt += (yq < yj || (yq == yj && q < b)) ? 1 : 0;
    }
    const int rk = 2 * cnt + ((t >= BB) ? 1 : 0);

    // ---- s_t = -||z_i - z_t|| / 2 (row max is exactly 0) ----
    const int joff = (t < BB) ? t * 2 * DD : ((t - BB) * 2 + 1) * DD;
    const float4* zj4 = reinterpret_cast<const float4*>(emb + joff);
    const float4* zi4 = reinterpret_cast<const float4*>(zi);
    float sq = 0.f;
#pragma unroll
    for (int d4 = 0; d4 < DD / 4; ++d4) {
        float4 v = zj4[d4];
        float4 u = zi4[d4];
        float d0 = u.x - v.x, d1 = u.y - v.y, d2 = u.z - v.z, d3 = u.w - v.w;
        sq += d0 * d0 + d1 * d1 + d2 * d2 + d3 * d3;
    }
    const float dist = (sq > 0.f) ? sqrtf(sq) : 0.f;
    const float s = -dist * 0.5f;

    const float yi = yb[(i < BB) ? i : i - BB];
    const float sg = yi - yj;                 // bitwise == reference
    const float ap = fabsf(sg);
    const float dwt = 1.f / (1.f + expf(-ap));
    float w = expf(s) * dwt;
    float dval = (sg < 0.f) ? (0.1f * w - w) : (0.f - w);  // c1 - w
    if (t == i) { w = 0.f; dval = 0.f; }      // exclude diagonal
    ys[rk] = yj;
    dsort[rk] = dval;
    __syncthreads();

    // ---- inclusive shuffle-scan of dsort + block sum of w ----
    float v = dsort[t];
    const int lane = t & 63, wid = t >> 6;
    for (int off = 1; off < 64; off <<= 1) {
        float o = __shfl_up(v, off);
        if (lane >= off) v += o;
    }
    if (lane == 63) wavesum[wid] = v;
    float wv = w;
    for (int off = 32; off; off >>= 1) wv += __shfl_down(wv, off);
    if (lane == 0) part[wid] = wv;
    __syncthreads();
    float base = 0.f;
    for (int k = 0; k < wid; ++k) base += wavesum[k];
    P[t + 1] = base + v;
    if (t == 0) {
        P[0] = 0.f;
        float W = 0.f;
        for (int k = 0; k < NN / 64; ++k) W += part[k];
        wtot_sh = W;
    }
    __syncthreads();
    const float Wtot = wtot_sh;

    // ---- interval [lo,hi) with |yi - ys[m]| < ap ----
    int l = 0, r = NN;
    while (l < r) { int m = (l + r) >> 1; if (yi - ys[m] < ap) r = m; else l = m + 1; }
    const int lo = l;
    l = 0; r = NN;
    while (l < r) { int m = (l + r) >> 1; if (!(ys[m] - yi < ap)) r = m; else l = m + 1; }
    const int hi = l;

    float denom = Wtot;
    if (hi > lo) denom += P[hi] - P[lo];

    float contrib = (t == i) ? 0.f : (s - logf(denom));

    for (int off = 32; off; off >>= 1) contrib += __shfl_down(contrib, off);
    if (lane == 0) part[wid] = contrib;
    __syncthreads();
    if (t == 0) {
        float ssum = 0.f;
        for (int k = 0; k < NN / 64; ++k) ssum += part[k];
        partial[i] = ssum;          // plain write, no atomic
    }

    // ---- grid-wide reduce, block 0 writes the scalar ----
    cg::this_grid().sync();
    if (i == 0) {
        float pv = partial[t];
        for (int off = 32; off; off >>= 1) pv += __shfl_down(pv, off);
        if (lane == 0) part[wid] = pv;
        __syncthreads();
        if (t == 0) {
            float ssum = 0.f;
            for (int k = 0; k < NN / 64; ++k) ssum += part[k];
            out[0] = -ssum * (1.f / (NN * (NN - 1.f)));
        }
    }
}

extern "C" void kernel_launch(void* const* d_in, const int* in_sizes, int n_in,
                              void* d_out, int out_size, void* d_ws, size_t ws_size,
                              hipStream_t stream) {
    const float* emb = (const float*)d_in[0];
    const float* tgt = (const float*)d_in[1];
    float* out = (float*)d_out;
    float* partial = (float*)d_ws;

    void* args[] = {(void*)&emb, (void*)&tgt, (void*)&partial, (void*)&out};
    hipLaunchCooperativeKernel((const void*)fused_kernel,
                               dim3(NN), dim3(NN), args, 0, stream);
}

// Round 4
// 28.313 us; speedup vs baseline: 2.6196x; 2.6196x over previous
//
#include <hip/hip_runtime.h>
#include <hip/hip_bf16.h>
#include <math.h>

#define NN 384   // 2*B
#define BB 192   // B
#define DD 128   // feature dim
#define DONE_MAGIC 0x5A5A5A5A

// TEMP=2.0 -> s = -dist*0.5 ; TAU=1.0 ; POS_W=0.1 ; NEG_W=1.0 ; SOFT=true
//
// denom[i,p] = Wtot_i + sum_{j: |yi-yj| < |yi-yp|} (c1_j - w_j)
// The j-set is a contiguous interval in y-sorted order; ranks are
// row-independent and computed per block from the 192 distinct targets.
//
// Single-node graph: 384 worker blocks + 1 fixup block (block NN) that
// spin-waits on per-worker flags (release/acquire, agent scope for
// cross-XCD visibility), reduces, writes out, and resets flags to 0 so
// every replay starts clean (workers rewrite flags each launch, so the
// one-time 0xAA poison is also harmless).

__global__ __launch_bounds__(NN) void fused_kernel(
    const float* __restrict__ emb,     // [192,2,128]
    const float* __restrict__ tgt,     // [192,1]
    float* __restrict__ partial,       // d_ws[0..NN)
    int* __restrict__ flags,           // d_ws[NN..2NN)
    float* __restrict__ out)           // [1]
{
    const int i = blockIdx.x;
    const int t = threadIdx.x;
    const int lane = t & 63, wid = t >> 6;

    __shared__ float part[NN / 64];

    if (i == NN) {
        // ---- fixup block: wait for all workers, reduce, write, reset ----
        float pv = 0.f;
        if (t < NN) {
            while (__hip_atomic_load(&flags[t], __ATOMIC_ACQUIRE,
                                     __HIP_MEMORY_SCOPE_AGENT) != DONE_MAGIC) {
                __builtin_amdgcn_s_sleep(1);
            }
            pv = __hip_atomic_load(&partial[t], __ATOMIC_RELAXED,
                                   __HIP_MEMORY_SCOPE_AGENT);
        }
        for (int off = 32; off; off >>= 1) pv += __shfl_down(pv, off);
        if (lane == 0) part[wid] = pv;
        __syncthreads();
        if (t == 0) {
            float ssum = 0.f;
            for (int k = 0; k < NN / 64; ++k) ssum += part[k];
            out[0] = -ssum * (1.f / (NN * (NN - 1.f)));
        }
        if (t < NN)
            __hip_atomic_store(&flags[t], 0, __ATOMIC_RELAXED,
                               __HIP_MEMORY_SCOPE_AGENT);
        return;
    }

    __shared__ float yb[BB];           // distinct targets
    __shared__ float zi[DD];
    __shared__ float ys[NN];           // y sorted
    __shared__ float dsort[NN];        // (c1-w) scattered to sorted order
    __shared__ float P[NN + 1];        // exclusive prefix sums
    __shared__ float wavesum[NN / 64];
    __shared__ float wtot_sh;

    if (t < BB) yb[t] = tgt[t];
    const int ioff = (i < BB) ? i * 2 * DD : ((i - BB) * 2 + 1) * DD;
    if (t < DD) zi[t] = emb[ioff + t];
    __syncthreads();

    // ---- rank of element t in stable y-sort (row-independent) ----
    const int b = (t < BB) ? t : t - BB;
    const float yj = yb[b];
    int cnt = 0;
#pragma unroll 4
    for (int q = 0; q < BB; ++q) {
        const float yq = yb[q];
        cnt += (yq < yj || (yq == yj && q < b)) ? 1 : 0;
    }
    const int rk = 2 * cnt + ((t >= BB) ? 1 : 0);

    // ---- s_t = -||z_i - z_t|| / 2 (row max is exactly 0) ----
    const int joff = (t < BB) ? t * 2 * DD : ((t - BB) * 2 + 1) * DD;
    const float4* zj4 = reinterpret_cast<const float4*>(emb + joff);
    const float4* zi4 = reinterpret_cast<const float4*>(zi);
    float sq = 0.f;
#pragma unroll
    for (int d4 = 0; d4 < DD / 4; ++d4) {
        float4 v = zj4[d4];
        float4 u = zi4[d4];
        float d0 = u.x - v.x, d1 = u.y - v.y, d2 = u.z - v.z, d3 = u.w - v.w;
        sq += d0 * d0 + d1 * d1 + d2 * d2 + d3 * d3;
    }
    const float dist = (sq > 0.f) ? sqrtf(sq) : 0.f;
    const float s = -dist * 0.5f;

    const float yi = yb[(i < BB) ? i : i - BB];
    const float sg = yi - yj;                 // bitwise == reference
    const float ap = fabsf(sg);
    const float dwt = 1.f / (1.f + expf(-ap));
    float w = expf(s) * dwt;
    float dval = (sg < 0.f) ? (0.1f * w - w) : (0.f - w);  // c1 - w
    if (t == i) { w = 0.f; dval = 0.f; }      // exclude diagonal
    ys[rk] = yj;
    dsort[rk] = dval;
    __syncthreads();

    // ---- inclusive shuffle-scan of dsort + block sum of w ----
    float v = dsort[t];
    for (int off = 1; off < 64; off <<= 1) {
        float o = __shfl_up(v, off);
        if (lane >= off) v += o;
    }
    if (lane == 63) wavesum[wid] = v;
    float wv = w;
    for (int off = 32; off; off >>= 1) wv += __shfl_down(wv, off);
    if (lane == 0) part[wid] = wv;
    __syncthreads();
    float base = 0.f;
    for (int k = 0; k < wid; ++k) base += wavesum[k];
    P[t + 1] = base + v;
    if (t == 0) {
        P[0] = 0.f;
        float W = 0.f;
        for (int k = 0; k < NN / 64; ++k) W += part[k];
        wtot_sh = W;
    }
    __syncthreads();
    const float Wtot = wtot_sh;

    // ---- interval [lo,hi) with |yi - ys[m]| < ap ----
    int l = 0, r = NN;
    while (l < r) { int m = (l + r) >> 1; if (yi - ys[m] < ap) r = m; else l = m + 1; }
    const int lo = l;
    l = 0; r = NN;
    while (l < r) { int m = (l + r) >> 1; if (!(ys[m] - yi < ap)) r = m; else l = m + 1; }
    const int hi = l;

    float denom = Wtot;
    if (hi > lo) denom += P[hi] - P[lo];

    float contrib = (t == i) ? 0.f : (s - logf(denom));

    for (int off = 32; off; off >>= 1) contrib += __shfl_down(contrib, off);
    if (lane == 0) part[wid] = contrib;
    __syncthreads();
    if (t == 0) {
        float ssum = 0.f;
        for (int k = 0; k < NN / 64; ++k) ssum += part[k];
        __hip_atomic_store(&partial[i], ssum, __ATOMIC_RELAXED,
                           __HIP_MEMORY_SCOPE_AGENT);
        __hip_atomic_store(&flags[i], DONE_MAGIC, __ATOMIC_RELEASE,
                           __HIP_MEMORY_SCOPE_AGENT);
    }
}

extern "C" void kernel_launch(void* const* d_in, const int* in_sizes, int n_in,
                              void* d_out, int out_size, void* d_ws, size_t ws_size,
                              hipStream_t stream) {
    const float* emb = (const float*)d_in[0];
    const float* tgt = (const float*)d_in[1];
    float* out = (float*)d_out;
    float* partial = (float*)d_ws;
    int* flags = (int*)((char*)d_ws + NN * sizeof(float));

    fused_kernel<<<NN + 1, NN, 0, stream>>>(emb, tgt, partial, flags, out);
}

// Round 5
// 27.354 us; speedup vs baseline: 2.7114x; 1.0351x over previous
//
#include <hip/hip_runtime.h>
#include <hip/hip_bf16.h>
#include <math.h>

#define NN 384   // 2*B
#define BB 192   // B
#define DD 128   // feature dim
#define DONE_MAGIC 0x5A5A5A5A

// TEMP=2.0 -> s = -dist*0.5 ; TAU=1.0 ; POS_W=0.1 ; NEG_W=1.0 ; SOFT=true
//
// denom[i,p] = Wtot_i + sum_{j: |yi-yj| < |yi-yp|} (c1_j - w_j)
// The j-set is a contiguous interval in y-sorted order; ranks are
// row-independent and computed per block from the 192 distinct targets.
//
// Single-node graph: 384 worker blocks + 1 fixup block (block NN).
// Workers: partial (relaxed, agent) then flag=DONE (release, agent).
// Fixup: RELAXED polls (no per-poll cache invalidates), one acquire
// fence (__threadfence) after all flags seen, reduce, write out, reset
// flags to 0 so every replay starts clean.

__global__ __launch_bounds__(NN) void fused_kernel(
    const float* __restrict__ emb,     // [192,2,128]
    const float* __restrict__ tgt,     // [192,1]
    float* __restrict__ partial,       // d_ws[0..NN)
    int* __restrict__ flags,           // d_ws[NN..2NN)
    float* __restrict__ out)           // [1]
{
    const int i = blockIdx.x;
    const int t = threadIdx.x;
    const int lane = t & 63, wid = t >> 6;

    __shared__ float part[NN / 64];

    if (i == NN) {
        // ---- fixup block: relaxed spin, one acquire fence, reduce ----
        if (t < NN) {
            while (__hip_atomic_load(&flags[t], __ATOMIC_RELAXED,
                                     __HIP_MEMORY_SCOPE_AGENT) != DONE_MAGIC) {
                __builtin_amdgcn_s_sleep(2);
            }
        }
        __threadfence();   // agent-scope acquire: partials now visible
        float pv = (t < NN) ? partial[t] : 0.f;
        for (int off = 32; off; off >>= 1) pv += __shfl_down(pv, off);
        if (lane == 0) part[wid] = pv;
        __syncthreads();
        if (t == 0) {
            float ssum = 0.f;
            for (int k = 0; k < NN / 64; ++k) ssum += part[k];
            out[0] = -ssum * (1.f / (NN * (NN - 1.f)));
        }
        if (t < NN)
            __hip_atomic_store(&flags[t], 0, __ATOMIC_RELAXED,
                               __HIP_MEMORY_SCOPE_AGENT);
        return;
    }

    __shared__ float yb[BB];           // distinct targets
    __shared__ float zi[DD];
    __shared__ float ys[NN];           // y sorted
    __shared__ float dsort[NN];        // (c1-w) scattered to sorted order
    __shared__ float P[NN + 1];        // exclusive prefix sums
    __shared__ float wavesum[NN / 64];
    __shared__ float wtot_sh;

    if (t < BB) yb[t] = tgt[t];
    const int ioff = (i < BB) ? i * 2 * DD : ((i - BB) * 2 + 1) * DD;
    if (t < DD) zi[t] = emb[ioff + t];
    __syncthreads();

    // ---- rank of element t in stable y-sort (row-independent) ----
    const int b = (t < BB) ? t : t - BB;
    const float yj = yb[b];
    int cnt = 0;
#pragma unroll 4
    for (int q = 0; q < BB; ++q) {
        const float yq = yb[q];
        cnt += (yq < yj || (yq == yj && q < b)) ? 1 : 0;
    }
    const int rk = 2 * cnt + ((t >= BB) ? 1 : 0);

    // ---- s_t = -||z_i - z_t|| / 2 (row max is exactly 0) ----
    const int joff = (t < BB) ? t * 2 * DD : ((t - BB) * 2 + 1) * DD;
    const float4* zj4 = reinterpret_cast<const float4*>(emb + joff);
    const float4* zi4 = reinterpret_cast<const float4*>(zi);
    float sq = 0.f;
#pragma unroll
    for (int d4 = 0; d4 < DD / 4; ++d4) {
        float4 v = zj4[d4];
        float4 u = zi4[d4];
        float d0 = u.x - v.x, d1 = u.y - v.y, d2 = u.z - v.z, d3 = u.w - v.w;
        sq += d0 * d0 + d1 * d1 + d2 * d2 + d3 * d3;
    }
    const float dist = (sq > 0.f) ? sqrtf(sq) : 0.f;
    const float s = -dist * 0.5f;

    const float yi = yb[(i < BB) ? i : i - BB];
    const float sg = yi - yj;                 // bitwise == reference
    const float ap = fabsf(sg);
    const float dwt = 1.f / (1.f + __expf(-ap));
    float w = __expf(s) * dwt;
    float dval = (sg < 0.f) ? (0.1f * w - w) : (0.f - w);  // c1 - w
    if (t == i) { w = 0.f; dval = 0.f; }      // exclude diagonal
    ys[rk] = yj;
    dsort[rk] = dval;
    __syncthreads();

    // ---- inclusive shuffle-scan of dsort + block sum of w ----
    float v = dsort[t];
    for (int off = 1; off < 64; off <<= 1) {
        float o = __shfl_up(v, off);
        if (lane >= off) v += o;
    }
    if (lane == 63) wavesum[wid] = v;
    float wv = w;
    for (int off = 32; off; off >>= 1) wv += __shfl_down(wv, off);
    if (lane == 0) part[wid] = wv;
    __syncthreads();
    float base = 0.f;
    for (int k = 0; k < wid; ++k) base += wavesum[k];
    P[t + 1] = base + v;
    if (t == 0) {
        P[0] = 0.f;
        float W = 0.f;
        for (int k = 0; k < NN / 64; ++k) W += part[k];
        wtot_sh = W;
    }
    __syncthreads();
    const float Wtot = wtot_sh;

    // ---- interval [lo,hi) with |yi - ys[m]| < ap ----
    // two independent 9-step binary searches, interleaved to overlap the
    // dependent-LDS-read latency chains (range 384 -> <=9 halvings)
    int l1 = 0, r1 = NN, l2 = 0, r2 = NN;
#pragma unroll
    for (int k = 0; k < 9; ++k) {
        if (l1 < r1) { int m = (l1 + r1) >> 1; if (yi - ys[m] < ap) r1 = m; else l1 = m + 1; }
        if (l2 < r2) { int m = (l2 + r2) >> 1; if (!(ys[m] - yi < ap)) r2 = m; else l2 = m + 1; }
    }
    const int lo = l1;
    const int hi = l2;

    float denom = Wtot;
    if (hi > lo) denom += P[hi] - P[lo];

    float contrib = (t == i) ? 0.f : (s - __logf(denom));

    for (int off = 32; off; off >>= 1) contrib += __shfl_down(contrib, off);
    if (lane == 0) part[wid] = contrib;
    __syncthreads();
    if (t == 0) {
        float ssum = 0.f;
        for (int k = 0; k < NN / 64; ++k) ssum += part[k];
        __hip_atomic_store(&partial[i], ssum, __ATOMIC_RELAXED,
                           __HIP_MEMORY_SCOPE_AGENT);
        __hip_atomic_store(&flags[i], DONE_MAGIC, __ATOMIC_RELEASE,
                           __HIP_MEMORY_SCOPE_AGENT);
    }
}

extern "C" void kernel_launch(void* const* d_in, const int* in_sizes, int n_in,
                              void* d_out, int out_size, void* d_ws, size_t ws_size,
                              hipStream_t stream) {
    const float* emb = (const float*)d_in[0];
    const float* tgt = (const float*)d_in[1];
    float* out = (float*)d_out;
    float* partial = (float*)d_ws;
    int* flags = (int*)((char*)d_ws + NN * sizeof(float));

    fused_kernel<<<NN + 1, NN, 0, stream>>>(emb, tgt, partial, flags, out);
}

// Round 6
// 22.236 us; speedup vs baseline: 3.3355x; 1.2302x over previous
//
#include <hip/hip_runtime.h>
#include <hip/hip_bf16.h>
#include <math.h>

#define NN 384   // 2*B
#define BB 192   // B
#define DD 128   // feature dim
#define DONE_MAGIC 0x5A5A5A5A

// TEMP=2.0 -> s = -dist*0.5 ; TAU=1.0 ; POS_W=0.1 ; NEG_W=1.0 ; SOFT=true
//
// denom[i,p] = Wtot_i + sum_{j: |yi-yj| < |yi-yp|} (c1_j - w_j)
// The j-set is a contiguous interval in y-sorted order.
//
// Row-pair symmetry: rows i and i+192 share the SAME y (targets are
// concatenated), hence identical sg/ap/dwt/ranks/sorted-y and identical
// search intervals. Only w_j (distance-derived) differs. One block
// handles the pair: z_j is loaded once, zi0/zi1 are one contiguous
// 256-float stage (emb[i,0,:] and emb[i,1,:]).
//
// Single-node graph: 192 worker blocks + 1 fixup block (block BB).
// Workers: partial (relaxed, agent) then flag=DONE (release, agent).
// Fixup: relaxed polls, one acquire fence, reduce, write out, reset
// flags to 0 (workers rewrite flags each launch, so the one-time 0xAA
// poison is harmless and replays start clean).

__global__ __launch_bounds__(NN) void fused_kernel(
    const float* __restrict__ emb,     // [192,2,128]
    const float* __restrict__ tgt,     // [192,1]
    float* __restrict__ partial,       // d_ws[0..BB)
    int* __restrict__ flags,           // d_ws[BB..2BB)
    float* __restrict__ out)           // [1]
{
    const int i = blockIdx.x;          // row pair (i, i+BB)
    const int t = threadIdx.x;         // column j
    const int lane = t & 63, wid = t >> 6;

    __shared__ float partC[NN / 64];

    if (i == BB) {
        // ---- fixup block: relaxed spin, one acquire fence, reduce ----
        if (t < BB) {
            while (__hip_atomic_load(&flags[t], __ATOMIC_RELAXED,
                                     __HIP_MEMORY_SCOPE_AGENT) != DONE_MAGIC) {
                __builtin_amdgcn_s_sleep(2);
            }
        }
        __threadfence();   // agent-scope acquire: partials now visible
        float pv = (t < BB) ? partial[t] : 0.f;
        for (int off = 32; off; off >>= 1) pv += __shfl_down(pv, off);
        if (lane == 0) partC[wid] = pv;
        __syncthreads();
        if (t == 0) {
            float ssum = 0.f;
            for (int k = 0; k < NN / 64; ++k) ssum += partC[k];
            out[0] = -ssum * (1.f / (NN * (NN - 1.f)));
        }
        if (t < BB)
            __hip_atomic_store(&flags[t], 0, __ATOMIC_RELAXED,
                               __HIP_MEMORY_SCOPE_AGENT);
        return;
    }

    __shared__ float yb[BB];            // distinct targets
    __shared__ float ziS[2 * DD];       // zi0 | zi1 (contiguous in emb)
    __shared__ float ys[NN];            // y sorted
    __shared__ float2 dsort[NN];        // (c1-w) for both rows, sorted order
    __shared__ float2 P[NN + 1];        // exclusive prefix sums (both rows)
    __shared__ float2 wavesum[NN / 64];
    __shared__ float2 partW[NN / 64];
    __shared__ float2 wtot_sh;

    if (t < BB) yb[t] = tgt[t];
    if (t < 2 * DD) ziS[t] = emb[i * 2 * DD + t];   // rows i and i+BB
    __syncthreads();

    // ---- rank of column t in stable y-sort (shared by the pair) ----
    const int b = (t < BB) ? t : t - BB;
    const float yj = yb[b];
    int cnt = 0;
#pragma unroll 4
    for (int q = 0; q < BB; ++q) {
        const float yq = yb[q];
        cnt += (yq < yj || (yq == yj && q < b)) ? 1 : 0;
    }
    const int rk = 2 * cnt + ((t >= BB) ? 1 : 0);

    // ---- distances to BOTH rows, z_j loaded once ----
    const int joff = (t < BB) ? t * 2 * DD : ((t - BB) * 2 + 1) * DD;
    const float4* zj4 = reinterpret_cast<const float4*>(emb + joff);
    const float4* z04 = reinterpret_cast<const float4*>(ziS);
    const float4* z14 = reinterpret_cast<const float4*>(ziS + DD);
    float sq0 = 0.f, sq1 = 0.f;
#pragma unroll
    for (int d4 = 0; d4 < DD / 4; ++d4) {
        float4 v = zj4[d4];
        float4 u0 = z04[d4];
        float4 u1 = z14[d4];
        float a0 = u0.x - v.x, a1 = u0.y - v.y, a2 = u0.z - v.z, a3 = u0.w - v.w;
        sq0 += a0 * a0 + a1 * a1 + a2 * a2 + a3 * a3;
        float b0 = u1.x - v.x, b1 = u1.y - v.y, b2 = u1.z - v.z, b3 = u1.w - v.w;
        sq1 += b0 * b0 + b1 * b1 + b2 * b2 + b3 * b3;
    }
    const float s0 = -((sq0 > 0.f) ? sqrtf(sq0) : 0.f) * 0.5f;
    const float s1 = -((sq1 > 0.f) ? sqrtf(sq1) : 0.f) * 0.5f;

    const float yi = yb[i];              // same for both rows of the pair
    const float sg = yi - yj;            // bitwise == reference
    const float ap = fabsf(sg);
    const float dwt = 1.f / (1.f + __expf(-ap));
    float w0 = __expf(s0) * dwt;
    float w1 = __expf(s1) * dwt;
    const float fac = (sg < 0.f) ? -0.9f : -1.0f;   // (c1-w) = fac*w
    float dv0 = fac * w0;
    float dv1 = fac * w1;
    if (t == i)      { w0 = 0.f; dv0 = 0.f; }   // diagonal of row i
    if (t == i + BB) { w1 = 0.f; dv1 = 0.f; }   // diagonal of row i+BB
    ys[rk] = yj;
    dsort[rk] = make_float2(dv0, dv1);
    __syncthreads();

    // ---- inclusive shuffle-scan of dsort + block sums of w ----
    float2 v = dsort[t];
    for (int off = 1; off < 64; off <<= 1) {
        float ox = __shfl_up(v.x, off);
        float oy = __shfl_up(v.y, off);
        if (lane >= off) { v.x += ox; v.y += oy; }
    }
    if (lane == 63) wavesum[wid] = v;
    float2 wv = make_float2(w0, w1);
    for (int off = 32; off; off >>= 1) {
        wv.x += __shfl_down(wv.x, off);
        wv.y += __shfl_down(wv.y, off);
    }
    if (lane == 0) partW[wid] = wv;
    __syncthreads();
    float2 base = make_float2(0.f, 0.f);
    for (int k = 0; k < wid; ++k) { base.x += wavesum[k].x; base.y += wavesum[k].y; }
    P[t + 1] = make_float2(base.x + v.x, base.y + v.y);
    if (t == 0) {
        P[0] = make_float2(0.f, 0.f);
        float2 W = make_float2(0.f, 0.f);
        for (int k = 0; k < NN / 64; ++k) { W.x += partW[k].x; W.y += partW[k].y; }
        wtot_sh = W;
    }
    __syncthreads();
    const float2 Wtot = wtot_sh;

    // ---- interval [lo,hi) with |yi - ys[m]| < ap  (shared by the pair) ----
    int l1 = 0, r1 = NN, l2 = 0, r2 = NN;
#pragma unroll
    for (int k = 0; k < 9; ++k) {
        if (l1 < r1) { int m = (l1 + r1) >> 1; if (yi - ys[m] < ap) r1 = m; else l1 = m + 1; }
        if (l2 < r2) { int m = (l2 + r2) >> 1; if (!(ys[m] - yi < ap)) r2 = m; else l2 = m + 1; }
    }
    const int lo = l1, hi = l2;

    float den0 = Wtot.x, den1 = Wtot.y;
    if (hi > lo) {
        den0 += P[hi].x - P[lo].x;
        den1 += P[hi].y - P[lo].y;
    }

    float contrib = 0.f;
    if (t != i)      contrib += s0 - __logf(den0);
    if (t != i + BB) contrib += s1 - __logf(den1);

    for (int off = 32; off; off >>= 1) contrib += __shfl_down(contrib, off);
    if (lane == 0) partC[wid] = contrib;
    __syncthreads();
    if (t == 0) {
        float ssum = 0.f;
        for (int k = 0; k < NN / 64; ++k) ssum += partC[k];
        __hip_atomic_store(&partial[i], ssum, __ATOMIC_RELAXED,
                           __HIP_MEMORY_SCOPE_AGENT);
        __hip_atomic_store(&flags[i], DONE_MAGIC, __ATOMIC_RELEASE,
                           __HIP_MEMORY_SCOPE_AGENT);
    }
}

extern "C" void kernel_launch(void* const* d_in, const int* in_sizes, int n_in,
                              void* d_out, int out_size, void* d_ws, size_t ws_size,
                              hipStream_t stream) {
    const float* emb = (const float*)d_in[0];
    const float* tgt = (const float*)d_in[1];
    float* out = (float*)d_out;
    float* partial = (float*)d_ws;
    int* flags = (int*)((char*)d_ws + BB * sizeof(float));

    fused_kernel<<<BB + 1, NN, 0, stream>>>(emb, tgt, partial, flags, out);
}

// Round 7
// 15.769 us; speedup vs baseline: 4.7035x; 1.4101x over previous
//
#include <hip/hip_runtime.h>
#include <hip/hip_bf16.h>
#include <math.h>

#define NN 384   // 2*B
#define BB 192   // B
#define DD 128   // feature dim
#define DONE_MAGIC 0x5A5A5A5Au

// TEMP=2.0 -> s = -dist*0.5 ; TAU=1.0 ; POS_W=0.1 ; NEG_W=1.0 ; SOFT=true
//
// denom[i,p] = Wtot_i + sum_{j: |yi-yj| < |yi-yp|} (c1_j - w_j)
// The j-set is a contiguous interval in y-sorted order.
//
// Row-pair symmetry: rows i and i+192 share the SAME y, hence identical
// sg/ap/dwt/ranks/sorted-y and search intervals; only w_j differs.
//
// Rank via u64 lexicographic keys: y in [0,1) is non-negative, so IEEE
// float order == unsigned bit order; key=(bits(y)<<9)|idx gives the exact
// stable-sort predicate (yq<yj) || (yq==yj && q<b) as ONE u64 compare.
//
// Completion protocol: each worker stores ONE relaxed 64-bit packet
// (hi=DONE_MAGIC, lo=float bits of its partial) at agent scope; the
// fixup block polls packets (data travels with the flag atomically, no
// fence needed), reduces, writes out, resets packets to 0 for replay.
// The one-time 0xAA poison has hi=0xAAAAAAAA != MAGIC, so it's harmless.

__global__ __launch_bounds__(NN) void fused_kernel(
    const float* __restrict__ emb,            // [192,2,128]
    const float* __restrict__ tgt,            // [192,1]
    unsigned long long* __restrict__ pkts,    // d_ws[0..BB) u64
    float* __restrict__ out)                  // [1]
{
    const int i = blockIdx.x;          // row pair (i, i+BB)
    const int t = threadIdx.x;         // column j
    const int lane = t & 63, wid = t >> 6;

    __shared__ float partC[NN / 64];

    if (i == BB) {
        // ---- fixup block: poll packed partial|flag, reduce, write, reset ----
        float pv = 0.f;
        if (t < BB) {
            unsigned long long pkt;
            for (;;) {
                pkt = __hip_atomic_load(&pkts[t], __ATOMIC_RELAXED,
                                        __HIP_MEMORY_SCOPE_AGENT);
                if ((unsigned)(pkt >> 32) == DONE_MAGIC) break;
                __builtin_amdgcn_s_sleep(2);
            }
            pv = __uint_as_float((unsigned)pkt);
        }
        for (int off = 32; off; off >>= 1) pv += __shfl_down(pv, off);
        if (lane == 0) partC[wid] = pv;
        __syncthreads();
        if (t == 0) {
            float ssum = 0.f;
            for (int k = 0; k < NN / 64; ++k) ssum += partC[k];
            out[0] = -ssum * (1.f / (NN * (NN - 1.f)));
        }
        if (t < BB)
            __hip_atomic_store(&pkts[t], 0ull, __ATOMIC_RELAXED,
                               __HIP_MEMORY_SCOPE_AGENT);
        return;
    }

    __shared__ float yb[BB];             // distinct targets
    __shared__ unsigned long long kb[BB];// (bits(y)<<9)|idx sort keys
    __shared__ float ziS[2 * DD];        // zi0 | zi1 (contiguous in emb)
    __shared__ float ys[NN];             // y sorted
    __shared__ float2 dsort[NN];         // (c1-w) both rows, sorted order
    __shared__ float2 P[NN + 1];         // exclusive prefix sums
    __shared__ float2 wavesum[NN / 64];
    __shared__ float2 partW[NN / 64];
    __shared__ float2 wtot_sh;

    if (t < BB) {
        const float y = tgt[t];
        yb[t] = y;
        kb[t] = ((unsigned long long)__float_as_uint(y) << 9) | (unsigned)t;
    }
    if (t < 2 * DD) ziS[t] = emb[i * 2 * DD + t];   // rows i and i+BB
    __syncthreads();

    const int b = (t < BB) ? t : t - BB;
    const float yj = yb[b];
    const unsigned long long kj =
        ((unsigned long long)__float_as_uint(yj) << 9) | (unsigned)b;

    // ---- fused: distances to BOTH rows + rank count (overlaps global-load
    //      latency with the rank compares; 6 key compares per float4 chunk) ----
    const int joff = (t < BB) ? t * 2 * DD : ((t - BB) * 2 + 1) * DD;
    const float4* zj4 = reinterpret_cast<const float4*>(emb + joff);
    const float4* z04 = reinterpret_cast<const float4*>(ziS);
    const float4* z14 = reinterpret_cast<const float4*>(ziS + DD);
    float sq0 = 0.f, sq1 = 0.f;
    int cnt = 0;
#pragma unroll 4
    for (int d4 = 0; d4 < DD / 4; ++d4) {
        float4 v = zj4[d4];
        float4 u0 = z04[d4];
        float4 u1 = z14[d4];
        float a0 = u0.x - v.x, a1 = u0.y - v.y, a2 = u0.z - v.z, a3 = u0.w - v.w;
        sq0 += a0 * a0 + a1 * a1 + a2 * a2 + a3 * a3;
        float b0 = u1.x - v.x, b1 = u1.y - v.y, b2 = u1.z - v.z, b3 = u1.w - v.w;
        sq1 += b0 * b0 + b1 * b1 + b2 * b2 + b3 * b3;
        const int q = 6 * d4;
        cnt += (kb[q + 0] < kj) ? 1 : 0;
        cnt += (kb[q + 1] < kj) ? 1 : 0;
        cnt += (kb[q + 2] < kj) ? 1 : 0;
        cnt += (kb[q + 3] < kj) ? 1 : 0;
        cnt += (kb[q + 4] < kj) ? 1 : 0;
        cnt += (kb[q + 5] < kj) ? 1 : 0;
    }
    const int rk = 2 * cnt + ((t >= BB) ? 1 : 0);
    const float s0 = -((sq0 > 0.f) ? sqrtf(sq0) : 0.f) * 0.5f;
    const float s1 = -((sq1 > 0.f) ? sqrtf(sq1) : 0.f) * 0.5f;

    const float yi = yb[i];              // same for both rows of the pair
    const float sg = yi - yj;            // bitwise == reference
    const float ap = fabsf(sg);
    const float dwt = 1.f / (1.f + __expf(-ap));
    float w0 = __expf(s0) * dwt;
    float w1 = __expf(s1) * dwt;
    const float fac = (sg < 0.f) ? -0.9f : -1.0f;   // (c1-w) = fac*w
    float dv0 = fac * w0;
    float dv1 = fac * w1;
    if (t == i)      { w0 = 0.f; dv0 = 0.f; }   // diagonal of row i
    if (t == i + BB) { w1 = 0.f; dv1 = 0.f; }   // diagonal of row i+BB
    ys[rk] = yj;
    dsort[rk] = make_float2(dv0, dv1);
    __syncthreads();

    // ---- inclusive shuffle-scan of dsort + block sums of w ----
    float2 v = dsort[t];
    for (int off = 1; off < 64; off <<= 1) {
        float ox = __shfl_up(v.x, off);
        float oy = __shfl_up(v.y, off);
        if (lane >= off) { v.x += ox; v.y += oy; }
    }
    if (lane == 63) wavesum[wid] = v;
    float2 wv = make_float2(w0, w1);
    for (int off = 32; off; off >>= 1) {
        wv.x += __shfl_down(wv.x, off);
        wv.y += __shfl_down(wv.y, off);
    }
    if (lane == 0) partW[wid] = wv;
    __syncthreads();
    float2 base = make_float2(0.f, 0.f);
    for (int k = 0; k < wid; ++k) { base.x += wavesum[k].x; base.y += wavesum[k].y; }
    P[t + 1] = make_float2(base.x + v.x, base.y + v.y);
    if (t == 0) {
        P[0] = make_float2(0.f, 0.f);
        float2 W = make_float2(0.f, 0.f);
        for (int k = 0; k < NN / 64; ++k) { W.x += partW[k].x; W.y += partW[k].y; }
        wtot_sh = W;
    }
    __syncthreads();
    const float2 Wtot = wtot_sh;

    // ---- interval [lo,hi) with |yi - ys[m]| < ap  (shared by the pair) ----
    int l1 = 0, r1 = NN, l2 = 0, r2 = NN;
#pragma unroll
    for (int k = 0; k < 9; ++k) {
        if (l1 < r1) { int m = (l1 + r1) >> 1; if (yi - ys[m] < ap) r1 = m; else l1 = m + 1; }
        if (l2 < r2) { int m = (l2 + r2) >> 1; if (!(ys[m] - yi < ap)) r2 = m; else l2 = m + 1; }
    }
    const int lo = l1, hi = l2;

    float den0 = Wtot.x, den1 = Wtot.y;
    if (hi > lo) {
        den0 += P[hi].x - P[lo].x;
        den1 += P[hi].y - P[lo].y;
    }

    float contrib = 0.f;
    if (t != i)      contrib += s0 - __logf(den0);
    if (t != i + BB) contrib += s1 - __logf(den1);

    for (int off = 32; off; off >>= 1) contrib += __shfl_down(contrib, off);
    if (lane == 0) partC[wid] = contrib;
    __syncthreads();
    if (t == 0) {
        float ssum = 0.f;
        for (int k = 0; k < NN / 64; ++k) ssum += partC[k];
        const unsigned long long pkt =
            ((unsigned long long)DONE_MAGIC << 32) |
            (unsigned long long)__float_as_uint(ssum);
        __hip_atomic_store(&pkts[i], pkt, __ATOMIC_RELAXED,
                           __HIP_MEMORY_SCOPE_AGENT);
    }
}

extern "C" void kernel_launch(void* const* d_in, const int* in_sizes, int n_in,
                              void* d_out, int out_size, void* d_ws, size_t ws_size,
                              hipStream_t stream) {
    const float* emb = (const float*)d_in[0];
    const float* tgt = (const float*)d_in[1];
    float* out = (float*)d_out;
    unsigned long long* pkts = (unsigned long long*)d_ws;

    fused_kernel<<<BB + 1, NN, 0, stream>>>(emb, tgt, pkts, out);
}